// Round 9
// baseline (383.055 us; speedup 1.0000x reference)
//
#include <hip/hip_runtime.h>
#include <hip/hip_bf16.h>

// Problem shapes (fixed by setup_inputs)
#define B_    1024
#define D_    768
#define POOL_ 100
#define KPAD  128                        // pool padded for transposed layout
#define PLEN_ 8
#define TOPK_ 3
#define EK_ELEMS (B_ * 4 * D_)           // 3,145,728
#define XB_ELEMS (B_ * 197 * D_)         // 154,976,256
#define XB_F4    (XB_ELEMS / 4)          // 38,744,064 float4s
#define COPY_BLOCKS 8192                 // R7-proven 6.4 TB/s config

#define BT 4                             // b-rows per score block
#define SCORE_THREADS 512
#define SCORE_BLOCKS (B_ / BT)           // 256

typedef float f4_t __attribute__((ext_vector_type(4)));

// ---------------------------------------------------------------------------
// Kernel 1: prep. For k<100: sm = softmax(A[k,:]), n = ||K[k,:]||, write
//   U_T[d][k] = sm_d * K[k,d]/n   (f64, k-contiguous transposed layout)
//   V_T[d][k] = sm_d * sm_d
// For k in [100,128): zero the pad columns (ws is poisoned 0xAA by harness).
// ---------------------------------------------------------------------------
__global__ void prep_kernel(const float* __restrict__ A, const float* __restrict__ K,
                            double* __restrict__ U_T, double* __restrict__ V_T) {
    const int k = blockIdx.x;
    const int t = threadIdx.x;

    if (k >= POOL_) {                    // zero pad columns, no A/K reads
        for (int d = t; d < D_; d += 256) {
            U_T[(size_t)d * KPAD + k] = 0.0;
            V_T[(size_t)d * KPAD + k] = 0.0;
        }
        return;
    }

    const int wave = t >> 6, lane = t & 63;
    __shared__ double red[4];

    double m = -1e300;
    for (int d = t; d < D_; d += 256) m = fmax(m, (double)A[k * D_ + d]);
    #pragma unroll
    for (int off = 32; off >= 1; off >>= 1) m = fmax(m, __shfl_xor(m, off));
    if (lane == 0) red[wave] = m;
    __syncthreads();
    m = fmax(fmax(red[0], red[1]), fmax(red[2], red[3]));
    __syncthreads();

    double s = 0.0;
    for (int d = t; d < D_; d += 256) s += exp((double)A[k * D_ + d] - m);
    #pragma unroll
    for (int off = 32; off >= 1; off >>= 1) s += __shfl_xor(s, off);
    if (lane == 0) red[wave] = s;
    __syncthreads();
    s = red[0] + red[1] + red[2] + red[3];
    __syncthreads();

    double ss = 0.0;
    for (int d = t; d < D_; d += 256) {
        double v = (double)K[k * D_ + d];
        ss += v * v;
    }
    #pragma unroll
    for (int off = 32; off >= 1; off >>= 1) ss += __shfl_xor(ss, off);
    if (lane == 0) red[wave] = ss;
    __syncthreads();
    ss = red[0] + red[1] + red[2] + red[3];
    const double n = fmax(sqrt(ss), 1e-12);

    for (int d = t; d < D_; d += 256) {
        const double smd = exp((double)A[k * D_ + d] - m) / s;
        U_T[(size_t)d * KPAD + k] = smd * ((double)K[k * D_ + d] / n);
        V_T[(size_t)d * KPAD + k] = smd * smd;
    }
}

// ---------------------------------------------------------------------------
// Kernel 2: score + top-3 + gather. 512 threads cover BT=4 b-rows.
// Thread role: klane = t&127 (k index, coalesced U_T/V_T loads), group = t>>7:
//   g&1 = d-half (0: d<384, 1: d>=384), g>>1 = b-pair (rows 0,1 vs 2,3).
// Each thread serially accumulates dot,sq for its 2 b-rows over its 384 d's —
// registers only, NO shuffles, NO per-k reduction chains (R8 lesson: those
// made score latency-bound, 115 us). d-halves combined via one LDS add.
// ---------------------------------------------------------------------------
__global__ void __launch_bounds__(SCORE_THREADS)
score_gather_kernel(const float* __restrict__ xq,
                    const double* __restrict__ U_T,
                    const double* __restrict__ V_T,
                    const float* __restrict__ p,
                    float* __restrict__ out) {
    __shared__ double s_xq[BT * D_];          // 24.6 KB
    __shared__ double s_part[2][KPAD][4];     // 8 KB  [bpair][k][dot0,dot1,sq0,sq1]
    __shared__ double s_aq[BT][KPAD];         // 4 KB
    __shared__ int    s_idx[BT][TOPK_];

    const int t = threadIdx.x;
    const int b0 = blockIdx.x * BT;
    const int klane = t & (KPAD - 1);
    const int g     = t >> 7;
    const int dhalf = g & 1;
    const int bpair = g >> 1;

    for (int i = t; i < BT * D_; i += SCORE_THREADS)
        s_xq[i] = (double)xq[(size_t)(b0 + i / D_) * D_ + (i % D_)];
    __syncthreads();

    const double* __restrict__ xr0 = &s_xq[(bpair * 2 + 0) * D_];
    const double* __restrict__ xr1 = &s_xq[(bpair * 2 + 1) * D_];
    double dot0 = 0.0, dot1 = 0.0, sq0 = 0.0, sq1 = 0.0;
    const int dbeg = dhalf * (D_ / 2), dend = dbeg + D_ / 2;
    #pragma unroll 8
    for (int d = dbeg; d < dend; ++d) {
        const double u  = U_T[(size_t)d * KPAD + klane];
        const double v  = V_T[(size_t)d * KPAD + klane];
        const double x0 = xr0[d], x1 = xr1[d];
        dot0 += x0 * u;  sq0 += (x0 * x0) * v;
        dot1 += x1 * u;  sq1 += (x1 * x1) * v;
    }

    if (dhalf == 1) {
        s_part[bpair][klane][0] = dot0;
        s_part[bpair][klane][1] = dot1;
        s_part[bpair][klane][2] = sq0;
        s_part[bpair][klane][3] = sq1;
    }
    __syncthreads();
    if (dhalf == 0 && klane < POOL_) {
        const double d0 = dot0 + s_part[bpair][klane][0];
        const double d1 = dot1 + s_part[bpair][klane][1];
        const double q0 = sq0  + s_part[bpair][klane][2];
        const double q1 = sq1  + s_part[bpair][klane][3];
        s_aq[bpair * 2 + 0][klane] = d0 / fmax(sqrt(q0), 1e-12);
        s_aq[bpair * 2 + 1][klane] = d1 / fmax(sqrt(q1), 1e-12);
    }
    __syncthreads();

    const int wave = t >> 6, lane = t & 63;
    if (wave < BT) {
        // wave w: top-3 for b-row w; lane covers k=lane, k=lane+64;
        // tie -> lowest index (matches lax.top_k stability)
        double v0 = s_aq[wave][lane];                               // lane<64<100
        double v1 = (lane + 64 < POOL_) ? s_aq[wave][lane + 64] : -1e300;
        #pragma unroll
        for (int r = 0; r < TOPK_; ++r) {
            double v; int ki;
            if (v0 >= v1) { v = v0; ki = lane; }
            else          { v = v1; ki = lane + 64; }
            #pragma unroll
            for (int off = 32; off >= 1; off >>= 1) {
                double ov = __shfl_xor(v, off);
                int    oi = __shfl_xor(ki, off);
                if (ov > v || (ov == v && oi < ki)) { v = ov; ki = oi; }
            }
            if (lane == 0) s_idx[wave][r] = ki;
            if (ki == lane)      v0 = -1e300;
            if (ki == lane + 64) v1 = -1e300;
        }
    }
    __syncthreads();

    // gather: BT rows x 8 prompt-rows x 192 float4 = 6144 units / 512 threads
    for (int w = t; w < BT * PLEN_ * 192; w += SCORE_THREADS) {
        const int bl  = w / (PLEN_ * 192);
        const int rem = w % (PLEN_ * 192);
        const int j = rem / 192, c = rem % 192;
        const int i0 = s_idx[bl][0], i1 = s_idx[bl][1], i2 = s_idx[bl][2];
        const int b = b0 + bl;
        const f4_t* __restrict__ q0 = (const f4_t*)(p + (size_t)(j * POOL_ + i0) * D_);
        const f4_t* __restrict__ q1 = (const f4_t*)(p + (size_t)(j * POOL_ + i1) * D_);
        const f4_t* __restrict__ q2 = (const f4_t*)(p + (size_t)(j * POOL_ + i2) * D_);
        f4_t v = q0[c] + q1[c] + q2[c];
        float* dst = (j < 4) ? out + ((size_t)b * 4 + j) * D_
                             : out + EK_ELEMS + ((size_t)b * 4 + (j - 4)) * D_;
        ((f4_t*)dst)[c] = v;
    }
}

// ---------------------------------------------------------------------------
// Kernel 3: x_block passthrough — R7-proven 6.4 TB/s plain grid-stride float4.
// ---------------------------------------------------------------------------
__global__ void __launch_bounds__(256)
copy_kernel(const f4_t* __restrict__ src, f4_t* __restrict__ dst) {
    size_t i = (size_t)blockIdx.x * 256 + threadIdx.x;
    const size_t stride = (size_t)COPY_BLOCKS * 256;
    for (; i < (size_t)XB_F4; i += stride)
        dst[i] = src[i];
}

extern "C" void kernel_launch(void* const* d_in, const int* in_sizes, int n_in,
                              void* d_out, int out_size, void* d_ws, size_t ws_size,
                              hipStream_t stream) {
    const float* x_querry = (const float*)d_in[0];   // (1024, 768)
    const float* x_block  = (const float*)d_in[1];   // (1024, 197, 768)
    const float* K        = (const float*)d_in[2];   // (100, 768)
    const float* A        = (const float*)d_in[3];   // (100, 768)
    const float* p        = (const float*)d_in[4];   // (8, 100, 768)
    // d_in[5] = l (unused)

    float* out = (float*)d_out;

    // workspace: U_T, V_T transposed f64 [768][128]
    double* U_T = (double*)d_ws;                     // 786,432 B
    double* V_T = U_T + (size_t)D_ * KPAD;           // 786,432 B

    prep_kernel<<<KPAD, 256, 0, stream>>>(A, K, U_T, V_T);
    score_gather_kernel<<<SCORE_BLOCKS, SCORE_THREADS, 0, stream>>>(
        x_querry, U_T, V_T, p, out);
    copy_kernel<<<COPY_BLOCKS, 256, 0, stream>>>(
        (const f4_t*)x_block, (f4_t*)(out + 2 * (size_t)EK_ELEMS));
}

// Round 10
// 282.602 us; speedup vs baseline: 1.3555x; 1.3555x over previous
//
#include <hip/hip_runtime.h>
#include <hip/hip_bf16.h>

// Problem shapes (fixed by setup_inputs)
#define B_    1024
#define D_    768
#define POOL_ 100
#define KPAD  128                        // pool padded for transposed layout
#define PLEN_ 8
#define TOPK_ 3
#define EK_ELEMS (B_ * 4 * D_)           // 3,145,728
#define XB_ELEMS (B_ * 197 * D_)         // 154,976,256
#define XB_F4    (XB_ELEMS / 4)          // 38,744,064 float4s

#define BT 4                             // b-rows per score block
#define SCORE_BLOCKS (B_ / BT)           // 256
#define COPY_BLOCKS  8192                // R7-proven 6.4 TB/s config
#define NBLOCKS (SCORE_BLOCKS + COPY_BLOCKS)

typedef float f4_t __attribute__((ext_vector_type(4)));

// ---------------------------------------------------------------------------
// Kernel 1: prep. For k<100: sm = softmax(A[k,:]), n = ||K[k,:]||, write
//   U_T[d][k] = sm_d * K[k,d]/n   (f64, k-contiguous transposed layout)
//   V_T[d][k] = sm_d * sm_d
// For k in [100,128): zero pad columns (so pad scores evaluate to 0, never
// selected, and no poisoned-f64 denormal traffic).
// ---------------------------------------------------------------------------
__global__ void prep_kernel(const float* __restrict__ A, const float* __restrict__ K,
                            double* __restrict__ U_T, double* __restrict__ V_T) {
    const int k = blockIdx.x;
    const int t = threadIdx.x;

    if (k >= POOL_) {
        for (int d = t; d < D_; d += 256) {
            U_T[(size_t)d * KPAD + k] = 0.0;
            V_T[(size_t)d * KPAD + k] = 0.0;
        }
        return;
    }

    const int wave = t >> 6, lane = t & 63;
    __shared__ double red[4];

    double m = -1e300;
    for (int d = t; d < D_; d += 256) m = fmax(m, (double)A[k * D_ + d]);
    #pragma unroll
    for (int off = 32; off >= 1; off >>= 1) m = fmax(m, __shfl_xor(m, off));
    if (lane == 0) red[wave] = m;
    __syncthreads();
    m = fmax(fmax(red[0], red[1]), fmax(red[2], red[3]));
    __syncthreads();

    double s = 0.0;
    for (int d = t; d < D_; d += 256) s += exp((double)A[k * D_ + d] - m);
    #pragma unroll
    for (int off = 32; off >= 1; off >>= 1) s += __shfl_xor(s, off);
    if (lane == 0) red[wave] = s;
    __syncthreads();
    s = red[0] + red[1] + red[2] + red[3];
    __syncthreads();

    double ss = 0.0;
    for (int d = t; d < D_; d += 256) {
        double v = (double)K[k * D_ + d];
        ss += v * v;
    }
    #pragma unroll
    for (int off = 32; off >= 1; off >>= 1) ss += __shfl_xor(ss, off);
    if (lane == 0) red[wave] = ss;
    __syncthreads();
    ss = red[0] + red[1] + red[2] + red[3];
    const double n = fmax(sqrt(ss), 1e-12);

    for (int d = t; d < D_; d += 256) {
        const double smd = exp((double)A[k * D_ + d] - m) / s;
        U_T[(size_t)d * KPAD + k] = smd * ((double)K[k * D_ + d] / n);
        V_T[(size_t)d * KPAD + k] = smd * smd;
    }
}

// ---------------------------------------------------------------------------
// Kernel 2 (fused score + copy, R8-champion structure):
//  blocks [0,256):    score BT=4 rows. 256 thr = 128 klane x 2 dhalf, each
//                     thread accumulates ALL 4 rows (R9 lesson: the bpair
//                     split doubled U/V L2 traffic for nothing). xq read via
//                     wave-uniform broadcast loads (L1-resident); hot loop
//                     has zero shuffles, zero LDS. Halves combined via LDS.
//  blocks [256,8448): R7-proven plain grid-stride float4 copy (6.4 TB/s).
//  Score is L2/f64-VALU-bound, copy is HBM-bound -> complementary pipes.
// ---------------------------------------------------------------------------
__global__ void __launch_bounds__(256)
fused_kernel(const float* __restrict__ xq,
             const double* __restrict__ U_T,
             const double* __restrict__ V_T,
             const float* __restrict__ p,
             const f4_t* __restrict__ xb,
             float* __restrict__ out) {
    const int t = threadIdx.x;

    if (blockIdx.x >= SCORE_BLOCKS) {
        // ---------------- copy role ----------------
        f4_t* __restrict__ dst = (f4_t*)(out + 2 * (size_t)EK_ELEMS);
        size_t i = (size_t)(blockIdx.x - SCORE_BLOCKS) * 256 + t;
        const size_t stride = (size_t)COPY_BLOCKS * 256;
        for (; i < (size_t)XB_F4; i += stride)
            dst[i] = xb[i];
        return;
    }

    // ---------------- score role ----------------
    __shared__ double s_hd[BT][KPAD];     // dhalf=1 partial dots
    __shared__ double s_hq[BT][KPAD];     // dhalf=1 partial sqs
    __shared__ double s_aq[BT][KPAD];
    __shared__ int    s_idx[BT][TOPK_];

    const int b0    = blockIdx.x * BT;
    const int klane = t & (KPAD - 1);
    const int dhalf = t >> 7;             // wave-uniform (waves 0,1 / 2,3)
    const int dbeg  = dhalf * (D_ / 2);

    const float* __restrict__ xr0 = xq + (size_t)(b0 + 0) * D_;
    const float* __restrict__ xr1 = xq + (size_t)(b0 + 1) * D_;
    const float* __restrict__ xr2 = xq + (size_t)(b0 + 2) * D_;
    const float* __restrict__ xr3 = xq + (size_t)(b0 + 3) * D_;

    double dot0 = 0, dot1 = 0, dot2 = 0, dot3 = 0;
    double sq0 = 0, sq1 = 0, sq2 = 0, sq3 = 0;
    #pragma unroll 4
    for (int i = 0; i < D_ / 2; ++i) {
        const int d = dbeg + i;
        const double u = U_T[(size_t)d * KPAD + klane];
        const double v = V_T[(size_t)d * KPAD + klane];
        const double x0 = (double)xr0[d]; dot0 += x0 * u; sq0 += x0 * x0 * v;
        const double x1 = (double)xr1[d]; dot1 += x1 * u; sq1 += x1 * x1 * v;
        const double x2 = (double)xr2[d]; dot2 += x2 * u; sq2 += x2 * x2 * v;
        const double x3 = (double)xr3[d]; dot3 += x3 * u; sq3 += x3 * x3 * v;
    }

    if (dhalf == 1) {
        s_hd[0][klane] = dot0; s_hd[1][klane] = dot1;
        s_hd[2][klane] = dot2; s_hd[3][klane] = dot3;
        s_hq[0][klane] = sq0;  s_hq[1][klane] = sq1;
        s_hq[2][klane] = sq2;  s_hq[3][klane] = sq3;
    }
    __syncthreads();
    if (dhalf == 0) {
        s_aq[0][klane] = (dot0 + s_hd[0][klane]) / fmax(sqrt(sq0 + s_hq[0][klane]), 1e-12);
        s_aq[1][klane] = (dot1 + s_hd[1][klane]) / fmax(sqrt(sq1 + s_hq[1][klane]), 1e-12);
        s_aq[2][klane] = (dot2 + s_hd[2][klane]) / fmax(sqrt(sq2 + s_hq[2][klane]), 1e-12);
        s_aq[3][klane] = (dot3 + s_hd[3][klane]) / fmax(sqrt(sq3 + s_hq[3][klane]), 1e-12);
    }
    __syncthreads();

    const int wave = t >> 6, lane = t & 63;
    {
        // wave w: top-3 for b-row w; lane covers k=lane and k=lane+64;
        // tie -> lowest index (matches lax.top_k stability)
        double v0 = s_aq[wave][lane];                                // lane<64<100
        double v1 = (lane + 64 < POOL_) ? s_aq[wave][lane + 64] : -1e300;
        #pragma unroll
        for (int r = 0; r < TOPK_; ++r) {
            double v; int ki;
            if (v0 >= v1) { v = v0; ki = lane; }
            else          { v = v1; ki = lane + 64; }
            #pragma unroll
            for (int off = 32; off >= 1; off >>= 1) {
                double ov = __shfl_xor(v, off);
                int    oi = __shfl_xor(ki, off);
                if (ov > v || (ov == v && oi < ki)) { v = ov; ki = oi; }
            }
            if (lane == 0) s_idx[wave][r] = ki;
            if (ki == lane)      v0 = -1e300;
            if (ki == lane + 64) v1 = -1e300;
        }
    }
    __syncthreads();

    // gather: BT rows x 8 prompt-rows x 192 float4 = 6144 units / 256 threads
    for (int w = t; w < BT * PLEN_ * 192; w += 256) {
        const int bl  = w / (PLEN_ * 192);
        const int rem = w % (PLEN_ * 192);
        const int j = rem / 192, c = rem % 192;
        const int i0 = s_idx[bl][0], i1 = s_idx[bl][1], i2 = s_idx[bl][2];
        const int b = b0 + bl;
        const f4_t* __restrict__ q0 = (const f4_t*)(p + (size_t)(j * POOL_ + i0) * D_);
        const f4_t* __restrict__ q1 = (const f4_t*)(p + (size_t)(j * POOL_ + i1) * D_);
        const f4_t* __restrict__ q2 = (const f4_t*)(p + (size_t)(j * POOL_ + i2) * D_);
        f4_t v = q0[c] + q1[c] + q2[c];
        float* dst = (j < 4) ? out + ((size_t)b * 4 + j) * D_
                             : out + EK_ELEMS + ((size_t)b * 4 + (j - 4)) * D_;
        ((f4_t*)dst)[c] = v;
    }
}

extern "C" void kernel_launch(void* const* d_in, const int* in_sizes, int n_in,
                              void* d_out, int out_size, void* d_ws, size_t ws_size,
                              hipStream_t stream) {
    const float* x_querry = (const float*)d_in[0];   // (1024, 768)
    const float* x_block  = (const float*)d_in[1];   // (1024, 197, 768)
    const float* K        = (const float*)d_in[2];   // (100, 768)
    const float* A        = (const float*)d_in[3];   // (100, 768)
    const float* p        = (const float*)d_in[4];   // (8, 100, 768)
    // d_in[5] = l (unused)

    float* out = (float*)d_out;

    // workspace: U_T, V_T transposed f64 [768][128]
    double* U_T = (double*)d_ws;                     // 786,432 B
    double* V_T = U_T + (size_t)D_ * KPAD;           // 786,432 B

    prep_kernel<<<KPAD, 256, 0, stream>>>(A, K, U_T, V_T);
    fused_kernel<<<NBLOCKS, 256, 0, stream>>>(x_querry, U_T, V_T, p,
                                              (const f4_t*)x_block, out);
}